// Round 1
// baseline (25.565 us; speedup 1.0000x reference)
//
#include <hip/hip_runtime.h>
#include <cfloat>
#include <climits>

#define TEMP_F 0.07f
#define SPLIT 8
#define THREADS 256

struct Partial {
    float m, s, pos_sum, minval;
    int   npos, minidx;
    int   pad0, pad1;   // 32 B
};

__device__ __forceinline__ void accum_elem(
    float lv, int cc, int tt, int cam, int trk, int gidx,
    float& m, float& s, float& pos_sum, int& npos, float& minval, int& minidx)
{
    if (cc == cam) {
        float a = lv * (1.0f / TEMP_F);
        if (a > m) { s *= expf(m - a); m = a; }
        s += expf(a - m);
        if (tt == trk) {
            npos   += 1;
            pos_sum += a;
            if (lv < minval || (lv == minval && gidx < minidx)) {
                minval = lv; minidx = gidx;
            }
        }
    }
}

__global__ __launch_bounds__(THREADS) void wscl_partial(
    const float* __restrict__ logits,
    const int*   __restrict__ cid,
    const int*   __restrict__ tidv,
    const int*   __restrict__ camids,
    const int*   __restrict__ trackids,
    Partial*     __restrict__ partials,
    int N)
{
    const int b  = blockIdx.x / SPLIT;
    const int sp = blockIdx.x % SPLIT;
    const int t  = threadIdx.x;
    const int cam = camids[b];
    const int trk = trackids[b];
    const float* lg = logits + (size_t)b * N;

    float m = -FLT_MAX, s = 0.0f, pos_sum = 0.0f, minval = FLT_MAX;
    int npos = 0, minidx = INT_MAX;

    if ((N & 3) == 0) {
        const int N4 = N >> 2;
        const int chunk = (N4 + SPLIT - 1) / SPLIT;
        const int i0 = sp * chunk;
        const int i1 = (i0 + chunk < N4) ? (i0 + chunk) : N4;
        const float4* lg4 = (const float4*)lg;
        const int4*   c4  = (const int4*)cid;
        const int4*   t4  = (const int4*)tidv;
        for (int i = i0 + t; i < i1; i += THREADS) {
            float4 v = lg4[i];
            int4   c = c4[i];
            int4   r = t4[i];
            int g = i * 4;
            accum_elem(v.x, c.x, r.x, cam, trk, g + 0, m, s, pos_sum, npos, minval, minidx);
            accum_elem(v.y, c.y, r.y, cam, trk, g + 1, m, s, pos_sum, npos, minval, minidx);
            accum_elem(v.z, c.z, r.z, cam, trk, g + 2, m, s, pos_sum, npos, minval, minidx);
            accum_elem(v.w, c.w, r.w, cam, trk, g + 3, m, s, pos_sum, npos, minval, minidx);
        }
    } else {
        const int chunk = (N + SPLIT - 1) / SPLIT;
        const int i0 = sp * chunk;
        const int i1 = (i0 + chunk < N) ? (i0 + chunk) : N;
        for (int i = i0 + t; i < i1; i += THREADS) {
            accum_elem(lg[i], cid[i], tidv[i], cam, trk, i, m, s, pos_sum, npos, minval, minidx);
        }
    }

    // block reduction
    __shared__ float sm[THREADS], ss[THREADS], sps[THREADS], sv[THREADS];
    __shared__ int   sn[THREADS], si[THREADS];
    sm[t] = m; ss[t] = s; sps[t] = pos_sum; sv[t] = minval; sn[t] = npos; si[t] = minidx;
    __syncthreads();
    for (int off = THREADS / 2; off > 0; off >>= 1) {
        if (t < off) {
            float m2 = sm[t + off], s2 = ss[t + off];
            float mm = fmaxf(sm[t], m2);
            // -FLT_MAX states: expf(-huge)=0, and s for such states is 0 anyway
            ss[t] = ss[t] * expf(sm[t] - mm) + s2 * expf(m2 - mm);
            sm[t] = mm;
            sps[t] += sps[t + off];
            sn[t]  += sn[t + off];
            float v2 = sv[t + off]; int i2 = si[t + off];
            if (v2 < sv[t] || (v2 == sv[t] && i2 < si[t])) { sv[t] = v2; si[t] = i2; }
        }
        __syncthreads();
    }
    if (t == 0) {
        Partial p;
        p.m = sm[0]; p.s = ss[0]; p.pos_sum = sps[0]; p.minval = sv[0];
        p.npos = sn[0]; p.minidx = si[0]; p.pad0 = 0; p.pad1 = 0;
        partials[blockIdx.x] = p;
    }
}

__global__ __launch_bounds__(THREADS) void wscl_finalize(
    const Partial* __restrict__ partials,
    const float*   __restrict__ mem,
    float*         __restrict__ out,
    float*         __restrict__ per_sample,
    int D)
{
    const int b = blockIdx.x;
    __shared__ int s_idx;
    if (threadIdx.x == 0) {
        float m = -FLT_MAX, s = 0.0f, pos = 0.0f, mv = FLT_MAX;
        int np = 0, mi = INT_MAX;
        for (int k = 0; k < SPLIT; ++k) {
            Partial p = partials[b * SPLIT + k];
            float mm = fmaxf(m, p.m);
            s = s * expf(m - mm) + p.s * expf(p.m - mm);
            m = mm;
            pos += p.pos_sum;
            np  += p.npos;
            if (p.minval < mv || (p.minval == mv && p.minidx < mi)) { mv = p.minval; mi = p.minidx; }
        }
        if (mi == INT_MAX) mi = 0;        // matches jnp.argmin on all-inf
        float fn = (float)np;
        // mean_log_prob_pos = ((pos - np*m) - np*log(s)) / np ; per_sample = -that
        float mlpp = ((pos - fn * m) - fn * logf(s)) / fn;
        per_sample[b] = -mlpp;            // TEMP/BASE_TEMP == 1
        s_idx = mi;
    }
    __syncthreads();
    const int mi = s_idx;
    for (int d = threadIdx.x; d < D; d += THREADS)
        out[1 + (size_t)b * D + d] = mem[(size_t)mi * D + d];
}

__global__ __launch_bounds__(THREADS) void wscl_loss(
    const float* __restrict__ per_sample, float* __restrict__ out, int B)
{
    __shared__ float buf[THREADS];
    float v = 0.0f;
    for (int i = threadIdx.x; i < B; i += THREADS) v += per_sample[i];
    buf[threadIdx.x] = v;
    __syncthreads();
    for (int off = THREADS / 2; off > 0; off >>= 1) {
        if (threadIdx.x < off) buf[threadIdx.x] += buf[threadIdx.x + off];
        __syncthreads();
    }
    if (threadIdx.x == 0) out[0] = buf[0] / (float)B;
}

extern "C" void kernel_launch(void* const* d_in, const int* in_sizes, int n_in,
                              void* d_out, int out_size, void* d_ws, size_t ws_size,
                              hipStream_t stream)
{
    const float* mem      = (const float*)d_in[0];
    const float* logits   = (const float*)d_in[1];
    const int*   cid      = (const int*)d_in[2];
    const int*   tidv     = (const int*)d_in[3];
    const int*   camids   = (const int*)d_in[4];
    const int*   trackids = (const int*)d_in[5];

    const int N = in_sizes[2];
    const int B = in_sizes[4];
    const int D = in_sizes[0] / N;

    float* out = (float*)d_out;

    Partial* partials = (Partial*)d_ws;
    size_t part_bytes = ((size_t)B * SPLIT * sizeof(Partial) + 255) & ~(size_t)255;
    float* per_sample = (float*)((char*)d_ws + part_bytes);

    wscl_partial<<<B * SPLIT, THREADS, 0, stream>>>(logits, cid, tidv, camids, trackids, partials, N);
    wscl_finalize<<<B, THREADS, 0, stream>>>(partials, mem, out, per_sample, D);
    wscl_loss<<<1, THREADS, 0, stream>>>(per_sample, out, B);
}